// Round 8
// baseline (2130.548 us; speedup 1.0000x reference)
//
#include <hip/hip_runtime.h>

#define M_EDGES 150000
#define NN_NODES 50000
#define N_TRIS  100000
#define F 256
#define NLAYERS 4

#define T0 1172                  // ceil(150000/128) tiles for x-GEMM
#define T1 391                   // ceil(50000/128)
#define T2 782                   // ceil(100000/128)
#define T0_PAD 1176              // 8*ceil(T0/8)
#define G0_BLOCKS (T0_PAD * 2)   // 2352, gemm-seg0 blocks in fused_a
#define T12 (T1 + T2)            // 1173
#define T12_PAD 1176
#define G12_BLOCKS (T12_PAD * 2) // 2352

#define ZN_BLOCKS (NN_NODES / 4) // 12500
#define WT_BLOCKS (N_TRIS / 4)   // 25000

typedef __attribute__((ext_vector_type(8))) __bf16 bf16x8;
typedef __attribute__((ext_vector_type(4))) float f32x4;

__device__ inline unsigned short f2bf(float f) {
    unsigned int u = __float_as_uint(f);
    u += 0x7fff + ((u >> 16) & 1);
    return (unsigned short)(u >> 16);
}
__device__ inline float bf2f(unsigned short h) {
    return __uint_as_float(((unsigned int)h) << 16);
}

__device__ inline void async16(const void* g, void* l) {
    __builtin_amdgcn_global_load_lds(
        (const __attribute__((address_space(1))) void*)g,
        (__attribute__((address_space(3))) void*)l, 16, 0, 0);
}

// ---------------------------------------------------------------------------
// Shared GEMM body: 128x128 C-tile, BK=32, XOR-swizzled LDS (r4: conflicts
// 7.2M->0), swapped-operand MFMA epilogue (ushort4 stores).
// ---------------------------------------------------------------------------
__device__ inline void gemm_tile_body(
    const unsigned short* __restrict__ Asrc, int nrows,
    const unsigned short* __restrict__ wseg,   // [n][k] 256x256
    unsigned short* __restrict__ dst,
    int tloc, int bn,
    unsigned short* As, unsigned short* Bs)
{
    const int tid  = threadIdx.x;
    const int bm0  = tloc * 128;
    const int wid  = tid >> 6;
    const int lane = tid & 63;
    const int lm   = lane & 15;
    const int lh   = lane >> 4;
    const int wm   = wid >> 1;
    const int wn   = wid & 1;
    const int wbase = tid & ~63;

    f32x4 cacc[4][4];
#pragma unroll
    for (int i = 0; i < 4; i++)
#pragma unroll
        for (int j = 0; j < 4; j++) cacc[i][j] = (f32x4){0.f, 0.f, 0.f, 0.f};

    for (int k0 = 0; k0 < 256; k0 += 32) {
#pragma unroll
        for (int s = 0; s < 2; s++) {
            int i   = s * 256 + tid;
            int row = i >> 2;
            int g   = (i & 3) ^ ((row >> 1) & 3);
            int gr  = bm0 + row;
            if (gr > nrows - 1) gr = nrows - 1;
            async16(Asrc + (size_t)gr * 256 + k0 + g * 8,
                    As + (size_t)(s * 256 + wbase) * 8);
            int nrow = bn * 128 + row;
            async16(wseg + (size_t)nrow * 256 + k0 + g * 8,
                    Bs + (size_t)(s * 256 + wbase) * 8);
        }
        asm volatile("s_waitcnt vmcnt(0)" ::: "memory");
        __syncthreads();

        bf16x8 a[4], bfr[4];
#pragma unroll
        for (int i = 0; i < 4; i++) {
            int rr = wm * 64 + i * 16 + lm;
            a[i] = *(const bf16x8*)(As + rr * 32 + ((lh ^ ((rr >> 1) & 3)) * 8));
        }
#pragma unroll
        for (int j = 0; j < 4; j++) {
            int rr = wn * 64 + j * 16 + lm;
            bfr[j] = *(const bf16x8*)(Bs + rr * 32 + ((lh ^ ((rr >> 1) & 3)) * 8));
        }
#pragma unroll
        for (int i = 0; i < 4; i++)
#pragma unroll
            for (int j = 0; j < 4; j++)
                cacc[i][j] = __builtin_amdgcn_mfma_f32_16x16x32_bf16(bfr[j], a[i], cacc[i][j], 0, 0, 0);
        __syncthreads();
    }

#pragma unroll
    for (int i = 0; i < 4; i++) {
        int grow = bm0 + wm * 64 + i * 16 + lm;
        if (grow < nrows) {
#pragma unroll
            for (int j = 0; j < 4; j++) {
                int col = bn * 128 + wn * 64 + j * 16 + lh * 4;
                ushort4 r;
                r.x = f2bf(cacc[i][j][0]);
                r.y = f2bf(cacc[i][j][1]);
                r.z = f2bf(cacc[i][j][2]);
                r.w = f2bf(cacc[i][j][3]);
                *(ushort4*)(dst + (size_t)grow * 256 + col) = r;
            }
        }
    }
}

// ---------------------------------------------------------------------------
// fused_a: blocks [0, G0_BLOCKS)            -> gemm seg0: y1 = x @ W1
//          blocks [G0, +ZN_BLOCKS)          -> s[n] = sum (+/-) x[e]
//          blocks [G0+ZN, +WT_BLOCKS)       -> q[t] = sum s_k * x[e_k]
// gemm blocks first so long MFMA blocks launch early; gather blocks co-reside
// and overlap their latency with the GEMM's barrier drains.
// ---------------------------------------------------------------------------
__global__ __launch_bounds__(256) void fused_a(
    const unsigned short* __restrict__ xb,
    const unsigned short* __restrict__ wt,     // seg0 = W1^T
    unsigned short* __restrict__ y1,
    const int* __restrict__ noff,
    const int* __restrict__ nadj,
    unsigned short* __restrict__ sbuf,
    const int* __restrict__ te,
    const int* __restrict__ ts,
    unsigned short* __restrict__ qbuf)
{
    __shared__ unsigned short As[128 * 32];
    __shared__ unsigned short Bs[128 * 32];

    const int b = blockIdx.x;
    if (b < G0_BLOCKS) {
        const int xcd = b & 7;
        const int c   = b >> 3;
        const int tile = (c >> 1) * 8 + xcd;
        const int bn   = c & 1;
        if (tile >= T0) return;
        gemm_tile_body(xb, M_EDGES, wt, y1, tile, bn, As, Bs);
        return;
    }
    int lane = threadIdx.x & 63;
    int f = lane * 4;
    int gb = b - G0_BLOCKS;
    if (gb < ZN_BLOCKS) {
        int n = gb * 4 + (threadIdx.x >> 6);
        int beg = noff[n], end = noff[n + 1];
        float ax = 0.f, ay = 0.f, az = 0.f, aw = 0.f;
        int i = beg;
        for (; i + 1 < end; i += 2) {
            int ea = nadj[i], eb = nadj[i + 1];
            float sa = (ea & 1) ? 1.f : -1.f;
            float sgb = (eb & 1) ? 1.f : -1.f;
            ushort4 va = *(const ushort4*)(xb + (size_t)(ea >> 1) * 256 + f);
            ushort4 vb = *(const ushort4*)(xb + (size_t)(eb >> 1) * 256 + f);
            ax += sa * bf2f(va.x) + sgb * bf2f(vb.x);
            ay += sa * bf2f(va.y) + sgb * bf2f(vb.y);
            az += sa * bf2f(va.z) + sgb * bf2f(vb.z);
            aw += sa * bf2f(va.w) + sgb * bf2f(vb.w);
        }
        if (i < end) {
            int ea = nadj[i];
            float sa = (ea & 1) ? 1.f : -1.f;
            ushort4 va = *(const ushort4*)(xb + (size_t)(ea >> 1) * 256 + f);
            ax += sa * bf2f(va.x);
            ay += sa * bf2f(va.y);
            az += sa * bf2f(va.z);
            aw += sa * bf2f(va.w);
        }
        ushort4 r;
        r.x = f2bf(ax); r.y = f2bf(ay); r.z = f2bf(az); r.w = f2bf(aw);
        *(ushort4*)(sbuf + (size_t)n * 256 + f) = r;
    } else {
        int t = (gb - ZN_BLOCKS) * 4 + (threadIdx.x >> 6);
        int e0 = te[3 * t + 0], e1 = te[3 * t + 1], e2 = te[3 * t + 2];
        float s0 = (float)ts[3 * t + 0];
        float s1 = (float)ts[3 * t + 1];
        float s2 = (float)ts[3 * t + 2];
        ushort4 a4 = *(const ushort4*)(xb + (size_t)e0 * 256 + f);
        ushort4 b4 = *(const ushort4*)(xb + (size_t)e1 * 256 + f);
        ushort4 d4 = *(const ushort4*)(xb + (size_t)e2 * 256 + f);
        ushort4 r;
        r.x = f2bf(s0 * bf2f(a4.x) + s1 * bf2f(b4.x) + s2 * bf2f(d4.x));
        r.y = f2bf(s0 * bf2f(a4.y) + s1 * bf2f(b4.y) + s2 * bf2f(d4.y));
        r.z = f2bf(s0 * bf2f(a4.z) + s1 * bf2f(b4.z) + s2 * bf2f(d4.z));
        r.w = f2bf(s0 * bf2f(a4.w) + s1 * bf2f(b4.w) + s2 * bf2f(d4.w));
        *(ushort4*)(qbuf + (size_t)t * 256 + f) = r;
    }
}

// ---------------------------------------------------------------------------
// gemm12: seg1: z = s @ W0 (50000 rows), seg2: w = q @ W2 (100000 rows)
// ---------------------------------------------------------------------------
__global__ __launch_bounds__(256) void gemm12(
    const unsigned short* __restrict__ sb,
    const unsigned short* __restrict__ qb,
    const unsigned short* __restrict__ wt,     // base of layer's 3-seg weights
    unsigned short* __restrict__ zb,
    unsigned short* __restrict__ wb)
{
    __shared__ unsigned short As[128 * 32];
    __shared__ unsigned short Bs[128 * 32];

    const int b    = blockIdx.x;
    const int xcd  = b & 7;
    const int c    = b >> 3;
    const int tile = (c >> 1) * 8 + xcd;
    const int bn   = c & 1;
    if (tile >= T12) return;

    if (tile < T1)
        gemm_tile_body(sb, NN_NODES, wt + 65536, zb, tile, bn, As, Bs);
    else
        gemm_tile_body(qb, N_TRIS, wt + 131072, wb, tile - T1, bn, As, Bs);
}

// ---------------------------------------------------------------------------
// CSR build
// ---------------------------------------------------------------------------
__global__ __launch_bounds__(256) void count_nodes(
    const int* __restrict__ en, int* __restrict__ cnt)
{
    int e = blockIdx.x * 256 + threadIdx.x;
    if (e < M_EDGES) {
        atomicAdd(&cnt[en[2 * e]], 1);
        atomicAdd(&cnt[en[2 * e + 1]], 1);
    }
}

__global__ __launch_bounds__(256) void count_tris(
    const int* __restrict__ te, int* __restrict__ cnt)
{
    int t = blockIdx.x * 256 + threadIdx.x;
    if (t < N_TRIS) {
#pragma unroll
        for (int k = 0; k < 3; k++) atomicAdd(&cnt[te[3 * t + k]], 1);
    }
}

__global__ __launch_bounds__(256) void scan_block(
    const int* __restrict__ cnt, int* __restrict__ off,
    int* __restrict__ partial, int n)
{
    __shared__ int s[256];
    int t = threadIdx.x;
    int gid = blockIdx.x * 256 + t;
    int v = (gid < n) ? cnt[gid] : 0;
    s[t] = v;
    __syncthreads();
    for (int o = 1; o < 256; o <<= 1) {
        int x = (t >= o) ? s[t - o] : 0;
        __syncthreads();
        s[t] += x;
        __syncthreads();
    }
    if (gid < n) off[gid] = s[t] - v;
    if (t == 255) partial[blockIdx.x] = s[255];
}

__global__ __launch_bounds__(1024) void scan_partial(int* __restrict__ partial, int nb)
{
    __shared__ int s[1024];
    int t = threadIdx.x;
    int v = (t < nb) ? partial[t] : 0;
    s[t] = v;
    __syncthreads();
    for (int o = 1; o < 1024; o <<= 1) {
        int x = (t >= o) ? s[t - o] : 0;
        __syncthreads();
        s[t] += x;
        __syncthreads();
    }
    if (t < nb) partial[t] = s[t] - v;
}

__global__ __launch_bounds__(256) void scan_add(
    int* __restrict__ off, int* __restrict__ cursor,
    const int* __restrict__ partial, int n, int total)
{
    int gid = blockIdx.x * 256 + threadIdx.x;
    if (gid == 0) off[n] = total;
    if (gid < n) {
        int o = off[gid] + partial[blockIdx.x];
        off[gid] = o;
        cursor[gid] = o;
    }
}

__global__ __launch_bounds__(256) void fill_nodes(
    const int* __restrict__ en, int* __restrict__ cursor, int* __restrict__ adj)
{
    int e = blockIdx.x * 256 + threadIdx.x;
    if (e < M_EDGES) {
        int u = en[2 * e], v = en[2 * e + 1];
        adj[atomicAdd(&cursor[u], 1)] = (e << 1);        // u endpoint: minus
        adj[atomicAdd(&cursor[v], 1)] = (e << 1) | 1;    // v endpoint: plus
    }
}

__global__ __launch_bounds__(256) void fill_tris(
    const int* __restrict__ te, const int* __restrict__ ts,
    int* __restrict__ cursor, int* __restrict__ adj)
{
    int t = blockIdx.x * 256 + threadIdx.x;
    if (t < N_TRIS) {
#pragma unroll
        for (int k = 0; k < 3; k++) {
            int e = te[3 * t + k];
            int neg = (ts[3 * t + k] < 0) ? 1 : 0;
            adj[atomicAdd(&cursor[e], 1)] = (t << 1) | neg;
        }
    }
}

// ---------------------------------------------------------------------------
// x_next[e] = relu( y1[e] + sum s*w[t] + z[v]-z[u] )
// ---------------------------------------------------------------------------
__global__ __launch_bounds__(256) void relu_fused(
    const unsigned short* __restrict__ y1,
    const unsigned short* __restrict__ w,
    const unsigned short* __restrict__ z,
    const int* __restrict__ en,
    const int* __restrict__ eoff,
    const int* __restrict__ eadj,
    unsigned short* __restrict__ xb)
{
    int e = blockIdx.x * 4 + (threadIdx.x >> 6);
    int lane = threadIdx.x & 63;
    int f = lane * 4;
    int u = en[2 * e], v = en[2 * e + 1];
    int beg = eoff[e], end = eoff[e + 1];
    ushort4 a4 = *(const ushort4*)(y1 + (size_t)e * 256 + f);
    ushort4 zv = *(const ushort4*)(z + (size_t)v * 256 + f);
    ushort4 zu = *(const ushort4*)(z + (size_t)u * 256 + f);
    float sx = bf2f(a4.x) + bf2f(zv.x) - bf2f(zu.x);
    float sy = bf2f(a4.y) + bf2f(zv.y) - bf2f(zu.y);
    float sz = bf2f(a4.z) + bf2f(zv.z) - bf2f(zu.z);
    float sw = bf2f(a4.w) + bf2f(zv.w) - bf2f(zu.w);
    int i = beg;
    for (; i + 1 < end; i += 2) {
        int ta = eadj[i], tb = eadj[i + 1];
        float sa = (ta & 1) ? -1.f : 1.f;
        float sgb = (tb & 1) ? -1.f : 1.f;
        ushort4 wa = *(const ushort4*)(w + (size_t)(ta >> 1) * 256 + f);
        ushort4 wbv = *(const ushort4*)(w + (size_t)(tb >> 1) * 256 + f);
        sx += sa * bf2f(wa.x) + sgb * bf2f(wbv.x);
        sy += sa * bf2f(wa.y) + sgb * bf2f(wbv.y);
        sz += sa * bf2f(wa.z) + sgb * bf2f(wbv.z);
        sw += sa * bf2f(wa.w) + sgb * bf2f(wbv.w);
    }
    if (i < end) {
        int ta = eadj[i];
        float sa = (ta & 1) ? -1.f : 1.f;
        ushort4 wa = *(const ushort4*)(w + (size_t)(ta >> 1) * 256 + f);
        sx += sa * bf2f(wa.x);
        sy += sa * bf2f(wa.y);
        sz += sa * bf2f(wa.z);
        sw += sa * bf2f(wa.w);
    }
    ushort4 r;
    r.x = f2bf(fmaxf(sx, 0.f));
    r.y = f2bf(fmaxf(sy, 0.f));
    r.z = f2bf(fmaxf(sz, 0.f));
    r.w = f2bf(fmaxf(sw, 0.f));
    *(ushort4*)(xb + (size_t)e * 256 + f) = r;
}

// ---------------------------------------------------------------------------
// p[e] = x[e] . W0_L ; out[n] = sum (+/-) p[e]
// ---------------------------------------------------------------------------
__global__ __launch_bounds__(256) void dotp(
    const unsigned short* __restrict__ xb,
    const float* __restrict__ wl,
    float* __restrict__ p)
{
    int e = blockIdx.x * 4 + (threadIdx.x >> 6);
    int lane = threadIdx.x & 63;
    ushort4 xv = *(const ushort4*)(xb + (size_t)e * 256 + lane * 4);
    float4 wv = *(const float4*)(wl + lane * 4);
    float s = bf2f(xv.x) * wv.x + bf2f(xv.y) * wv.y +
              bf2f(xv.z) * wv.z + bf2f(xv.w) * wv.w;
#pragma unroll
    for (int off = 32; off > 0; off >>= 1)
        s += __shfl_down(s, off, 64);
    if (lane == 0) p[e] = s;
}

__global__ __launch_bounds__(256) void out_nodes(
    const float* __restrict__ p,
    const int* __restrict__ noff,
    const int* __restrict__ nadj,
    float* __restrict__ out)
{
    int n = blockIdx.x * 256 + threadIdx.x;
    if (n >= NN_NODES) return;
    int beg = noff[n], end = noff[n + 1];
    float s = 0.f;
    for (int i = beg; i < end; i++) {
        int ent = nadj[i];
        float sg = (ent & 1) ? 1.f : -1.f;
        s += sg * p[ent >> 1];
    }
    out[n] = s;
}

// ---------------------------------------------------------------------------
// Conversions
// ---------------------------------------------------------------------------
__global__ __launch_bounds__(256) void cvt_x(
    const float* __restrict__ x, unsigned short* __restrict__ xb)
{
    int idx = blockIdx.x * 256 + threadIdx.x;
    float4 v = *(const float4*)(x + (size_t)idx * 4);
    ushort4 r;
    r.x = f2bf(v.x); r.y = f2bf(v.y); r.z = f2bf(v.z); r.w = f2bf(v.w);
    *(ushort4*)(xb + (size_t)idx * 4) = r;
}

// wt[l][seg][n][k], seg order = (W1, W0, W2)
__global__ __launch_bounds__(256) void cvt_w(
    const float* __restrict__ W0, const float* __restrict__ W1,
    const float* __restrict__ W2, unsigned short* __restrict__ wt)
{
    int idx = blockIdx.x * 256 + threadIdx.x;   // 4*3*65536 total
    int l = idx / (3 * 65536);
    int rem = idx - l * (3 * 65536);
    int seg = rem >> 16;
    int n = (rem >> 8) & 255;
    int k = rem & 255;
    const float* src = (seg == 0) ? W1 : (seg == 1) ? W0 : W2;
    wt[idx] = f2bf(src[(size_t)l * 65536 + k * 256 + n]);
}

extern "C" void kernel_launch(void* const* d_in, const int* in_sizes, int n_in,
                              void* d_out, int out_size, void* d_ws, size_t ws_size,
                              hipStream_t stream)
{
    const float* x0  = (const float*)d_in[0];
    const float* W0s = (const float*)d_in[1];
    const float* W1s = (const float*)d_in[2];
    const float* W2s = (const float*)d_in[3];
    const float* WL  = (const float*)d_in[4];
    const int*   en  = (const int*)d_in[5];
    const int*   te  = (const int*)d_in[6];
    const int*   ts  = (const int*)d_in[7];
    float* out = (float*)d_out;

    const size_t MF = (size_t)M_EDGES * F;
    unsigned short* xb = (unsigned short*)d_ws;          // MF
    unsigned short* y1 = xb + MF;                        // MF
    unsigned short* sbuf = y1 + MF;                      // NN*256
    unsigned short* qbuf = sbuf + (size_t)NN_NODES * 256;// N_TRIS*256
    unsigned short* wt = qbuf + (size_t)N_TRIS * 256;    // 4*3*65536
    unsigned short* wb = wt + (size_t)4 * 3 * 65536;     // N_TRIS*256
    unsigned short* zb = wb + (size_t)N_TRIS * 256;      // NN*256
    float* p = (float*)(zb + (size_t)NN_NODES * 256);    // M f32
    int* noff = (int*)(p + M_EDGES);                     // NN+1
    int* ncur = noff + (NN_NODES + 1);                   // NN
    int* nadj = ncur + NN_NODES;                         // 2*M
    int* eoff = nadj + 2 * M_EDGES;                      // M+1
    int* ecur = eoff + (M_EDGES + 1);                    // M
    int* eadj = ecur + M_EDGES;                          // 3*N_TRIS
    int* part = eadj + 3 * N_TRIS;                       // 1024

    cvt_w<<<(4 * 3 * 65536) / 256, 256, 0, stream>>>(W0s, W1s, W2s, wt);
    cvt_x<<<(int)(MF / 4 / 256), 256, 0, stream>>>(x0, xb);

    const int nbN = (NN_NODES + 255) / 256;
    const int nbE = (M_EDGES + 255) / 256;
    hipMemsetAsync(ncur, 0, NN_NODES * sizeof(int), stream);
    hipMemsetAsync(ecur, 0, M_EDGES * sizeof(int), stream);
    count_nodes<<<nbE, 256, 0, stream>>>(en, ncur);
    count_tris<<<(N_TRIS + 255) / 256, 256, 0, stream>>>(te, ecur);
    scan_block<<<nbN, 256, 0, stream>>>(ncur, noff, part, NN_NODES);
    scan_partial<<<1, 1024, 0, stream>>>(part, nbN);
    scan_add<<<nbN, 256, 0, stream>>>(noff, ncur, part, NN_NODES, 2 * M_EDGES);
    fill_nodes<<<nbE, 256, 0, stream>>>(en, ncur, nadj);
    scan_block<<<nbE, 256, 0, stream>>>(ecur, eoff, part, M_EDGES);
    scan_partial<<<1, 1024, 0, stream>>>(part, nbE);
    scan_add<<<nbE, 256, 0, stream>>>(eoff, ecur, part, M_EDGES, 3 * N_TRIS);
    fill_tris<<<(N_TRIS + 255) / 256, 256, 0, stream>>>(te, ts, ecur, eadj);

    const int fa_blocks = G0_BLOCKS + ZN_BLOCKS + WT_BLOCKS;   // 39852
    for (int l = 0; l < NLAYERS; l++) {
        const unsigned short* wl_ = wt + (size_t)l * 3 * 65536;
        fused_a<<<fa_blocks, 256, 0, stream>>>(
            xb, wl_, y1, noff, nadj, sbuf, te, ts, qbuf);
        gemm12<<<G12_BLOCKS, 256, 0, stream>>>(sbuf, qbuf, wl_, zb, wb);
        relu_fused<<<M_EDGES / 4, 256, 0, stream>>>(y1, wb, zb, en, eoff, eadj, xb);
    }

    dotp<<<M_EDGES / 4, 256, 0, stream>>>(xb, WL, p);
    out_nodes<<<(NN_NODES + 255) / 256, 256, 0, stream>>>(p, noff, nadj, out);
}

// Round 9
// 1381.194 us; speedup vs baseline: 1.5425x; 1.5425x over previous
//
#include <hip/hip_runtime.h>

#define M_EDGES 150000
#define NN_NODES 50000
#define N_TRIS  100000
#define F 256
#define NLAYERS 4

// unified GEMM: virtual A = [x (150k) ; s (50k) ; q (100k)], 128-row tiles,
// each block computes all 256 output cols (no bn split)
#define T0 1172                  // ceil(150000/128)
#define T1 391                   // ceil(50000/128)
#define T2 782                   // ceil(100000/128)
#define NTILES (T0 + T1 + T2)    // 2345

#define ZN_BLOCKS (NN_NODES / 4) // 12500
#define WT_BLOCKS (N_TRIS / 4)   // 25000

typedef __attribute__((ext_vector_type(8))) __bf16 bf16x8;
typedef __attribute__((ext_vector_type(4))) float f32x4;

__device__ inline unsigned short f2bf(float f) {
    unsigned int u = __float_as_uint(f);
    u += 0x7fff + ((u >> 16) & 1);
    return (unsigned short)(u >> 16);
}
__device__ inline float bf2f(unsigned short h) {
    return __uint_as_float(((unsigned int)h) << 16);
}

__device__ inline void async16(const void* g, void* l) {
    __builtin_amdgcn_global_load_lds(
        (const __attribute__((address_space(1))) void*)g,
        (__attribute__((address_space(3))) void*)l, 16, 0, 0);
}

// ---------------------------------------------------------------------------
// Unified bf16 MFMA GEMM, 3 row-segments, 128 rows x 256 cols per block:
//   seg0: y1 = x @ W1 (150000 rows)   seg1: z = s @ W0   seg2: w = q @ W2
// One block stages its A-tile once and computes the FULL 256-col output
// (2345 blocks; halves the per-block-barrier budget vs the 4704-block bn
// split, and kills the 2x A-refetch). acc = 4x8 f32x4 = 128 VGPR -> ~2
// waves/SIMD; acceptable in the latency-bound regime (r7 analysis).
// XOR-swizzled LDS (r4: conflicts 7.2M -> 0), swapped-operand MFMA epilogue.
// ---------------------------------------------------------------------------
__global__ __launch_bounds__(256) void gemm_mfma(
    const unsigned short* __restrict__ xb,
    const unsigned short* __restrict__ sb,
    const unsigned short* __restrict__ qb,
    const unsigned short* __restrict__ wt,
    unsigned short* __restrict__ y1,
    unsigned short* __restrict__ zb,
    unsigned short* __restrict__ wb)
{
    __shared__ unsigned short As[128 * 32];   // 8 KB
    __shared__ unsigned short Bs[256 * 32];   // 16 KB

    const int tile = blockIdx.x;
    int seg, tloc;
    if (tile < T0)            { seg = 0; tloc = tile; }
    else if (tile < T0 + T1)  { seg = 1; tloc = tile - T0; }
    else                      { seg = 2; tloc = tile - T0 - T1; }
    const unsigned short* Asrc = (seg == 0) ? xb : (seg == 1) ? sb : qb;
    const int nrows = (seg == 0) ? M_EDGES : (seg == 1) ? NN_NODES : N_TRIS;
    const unsigned short* wseg = wt + seg * 65536;   // [n][k] 256x256
    unsigned short* dst = (seg == 0) ? y1 : (seg == 1) ? zb : wb;

    const int tid  = threadIdx.x;
    const int bm0  = tloc * 128;
    const int wid  = tid >> 6;
    const int lane = tid & 63;
    const int lm   = lane & 15;
    const int lh   = lane >> 4;
    const int wm   = wid >> 1;          // 64-row half
    const int wn   = wid & 1;           // 128-col half
    const int wbase = tid & ~63;

    f32x4 cacc[4][8];
#pragma unroll
    for (int i = 0; i < 4; i++)
#pragma unroll
        for (int j = 0; j < 8; j++) cacc[i][j] = (f32x4){0.f, 0.f, 0.f, 0.f};

    for (int k0 = 0; k0 < 256; k0 += 32) {
        // stage A: 128 rows x 32k (2 rounds), B: 256 n-rows x 32k (4 rounds)
#pragma unroll
        for (int s = 0; s < 2; s++) {
            int i   = s * 256 + tid;
            int row = i >> 2;
            int g   = (i & 3) ^ ((row >> 1) & 3);
            int gr  = bm0 + row;
            if (gr > nrows - 1) gr = nrows - 1;
            async16(Asrc + (size_t)gr * 256 + k0 + g * 8,
                    As + (size_t)(s * 256 + wbase) * 8);
        }
#pragma unroll
        for (int s = 0; s < 4; s++) {
            int i   = s * 256 + tid;
            int row = i >> 2;
            int g   = (i & 3) ^ ((row >> 1) & 3);
            async16(wseg + (size_t)row * 256 + k0 + g * 8,
                    Bs + (size_t)(s * 256 + wbase) * 8);
        }
        asm volatile("s_waitcnt vmcnt(0)" ::: "memory");
        __syncthreads();

        bf16x8 a[4], bfr[8];
#pragma unroll
        for (int i = 0; i < 4; i++) {
            int rr = wm * 64 + i * 16 + lm;
            a[i] = *(const bf16x8*)(As + rr * 32 + ((lh ^ ((rr >> 1) & 3)) * 8));
        }
#pragma unroll
        for (int j = 0; j < 8; j++) {
            int rr = wn * 128 + j * 16 + lm;
            bfr[j] = *(const bf16x8*)(Bs + rr * 32 + ((lh ^ ((rr >> 1) & 3)) * 8));
        }
#pragma unroll
        for (int i = 0; i < 4; i++)
#pragma unroll
            for (int j = 0; j < 8; j++)
                cacc[i][j] = __builtin_amdgcn_mfma_f32_16x16x32_bf16(bfr[j], a[i], cacc[i][j], 0, 0, 0);
        __syncthreads();
    }

#pragma unroll
    for (int i = 0; i < 4; i++) {
        int grow = bm0 + wm * 64 + i * 16 + lm;
        if (grow < nrows) {
#pragma unroll
            for (int j = 0; j < 8; j++) {
                int col = wn * 128 + j * 16 + lh * 4;
                ushort4 r;
                r.x = f2bf(cacc[i][j][0]);
                r.y = f2bf(cacc[i][j][1]);
                r.z = f2bf(cacc[i][j][2]);
                r.w = f2bf(cacc[i][j][3]);
                *(ushort4*)(dst + (size_t)grow * 256 + col) = r;
            }
        }
    }
}

// ---------------------------------------------------------------------------
// CSR build
// ---------------------------------------------------------------------------
__global__ __launch_bounds__(256) void count_nodes(
    const int* __restrict__ en, int* __restrict__ cnt)
{
    int e = blockIdx.x * 256 + threadIdx.x;
    if (e < M_EDGES) {
        atomicAdd(&cnt[en[2 * e]], 1);
        atomicAdd(&cnt[en[2 * e + 1]], 1);
    }
}

__global__ __launch_bounds__(256) void count_tris(
    const int* __restrict__ te, int* __restrict__ cnt)
{
    int t = blockIdx.x * 256 + threadIdx.x;
    if (t < N_TRIS) {
#pragma unroll
        for (int k = 0; k < 3; k++) atomicAdd(&cnt[te[3 * t + k]], 1);
    }
}

__global__ __launch_bounds__(256) void scan_block(
    const int* __restrict__ cnt, int* __restrict__ off,
    int* __restrict__ partial, int n)
{
    __shared__ int s[256];
    int t = threadIdx.x;
    int gid = blockIdx.x * 256 + t;
    int v = (gid < n) ? cnt[gid] : 0;
    s[t] = v;
    __syncthreads();
    for (int o = 1; o < 256; o <<= 1) {
        int x = (t >= o) ? s[t - o] : 0;
        __syncthreads();
        s[t] += x;
        __syncthreads();
    }
    if (gid < n) off[gid] = s[t] - v;
    if (t == 255) partial[blockIdx.x] = s[255];
}

__global__ __launch_bounds__(1024) void scan_partial(int* __restrict__ partial, int nb)
{
    __shared__ int s[1024];
    int t = threadIdx.x;
    int v = (t < nb) ? partial[t] : 0;
    s[t] = v;
    __syncthreads();
    for (int o = 1; o < 1024; o <<= 1) {
        int x = (t >= o) ? s[t - o] : 0;
        __syncthreads();
        s[t] += x;
        __syncthreads();
    }
    if (t < nb) partial[t] = s[t] - v;
}

__global__ __launch_bounds__(256) void scan_add(
    int* __restrict__ off, int* __restrict__ cursor,
    const int* __restrict__ partial, int n, int total)
{
    int gid = blockIdx.x * 256 + threadIdx.x;
    if (gid == 0) off[n] = total;
    if (gid < n) {
        int o = off[gid] + partial[blockIdx.x];
        off[gid] = o;
        cursor[gid] = o;
    }
}

__global__ __launch_bounds__(256) void fill_nodes(
    const int* __restrict__ en, int* __restrict__ cursor, int* __restrict__ adj)
{
    int e = blockIdx.x * 256 + threadIdx.x;
    if (e < M_EDGES) {
        int u = en[2 * e], v = en[2 * e + 1];
        adj[atomicAdd(&cursor[u], 1)] = (e << 1);        // u endpoint: minus
        adj[atomicAdd(&cursor[v], 1)] = (e << 1) | 1;    // v endpoint: plus
    }
}

__global__ __launch_bounds__(256) void fill_tris(
    const int* __restrict__ te, const int* __restrict__ ts,
    int* __restrict__ cursor, int* __restrict__ adj)
{
    int t = blockIdx.x * 256 + threadIdx.x;
    if (t < N_TRIS) {
#pragma unroll
        for (int k = 0; k < 3; k++) {
            int e = te[3 * t + k];
            int neg = (ts[3 * t + k] < 0) ? 1 : 0;
            adj[atomicAdd(&cursor[e], 1)] = (t << 1) | neg;
        }
    }
}

// ---------------------------------------------------------------------------
// Aggregation pass (pre-GEMM):
//   blocks [0, ZN_BLOCKS)   : s[n] = sum (+/-) x[e]   (node CSR)
//   blocks [ZN, +WT)        : q[t] = sum s_k * x[e_k] (tri direct)
// ---------------------------------------------------------------------------
__global__ __launch_bounds__(256) void agg_fused(
    const unsigned short* __restrict__ xb,
    const int* __restrict__ noff,
    const int* __restrict__ nadj,
    unsigned short* __restrict__ sbuf,
    const int* __restrict__ te,
    const int* __restrict__ ts,
    unsigned short* __restrict__ qbuf)
{
    int lane = threadIdx.x & 63;
    int f = lane * 4;
    if (blockIdx.x < ZN_BLOCKS) {
        int n = blockIdx.x * 4 + (threadIdx.x >> 6);
        int beg = noff[n], end = noff[n + 1];
        float ax = 0.f, ay = 0.f, az = 0.f, aw = 0.f;
        int i = beg;
        for (; i + 1 < end; i += 2) {
            int ea = nadj[i], eb = nadj[i + 1];
            float sa = (ea & 1) ? 1.f : -1.f;
            float sgb = (eb & 1) ? 1.f : -1.f;
            ushort4 va = *(const ushort4*)(xb + (size_t)(ea >> 1) * 256 + f);
            ushort4 vb = *(const ushort4*)(xb + (size_t)(eb >> 1) * 256 + f);
            ax += sa * bf2f(va.x) + sgb * bf2f(vb.x);
            ay += sa * bf2f(va.y) + sgb * bf2f(vb.y);
            az += sa * bf2f(va.z) + sgb * bf2f(vb.z);
            aw += sa * bf2f(va.w) + sgb * bf2f(vb.w);
        }
        if (i < end) {
            int ea = nadj[i];
            float sa = (ea & 1) ? 1.f : -1.f;
            ushort4 va = *(const ushort4*)(xb + (size_t)(ea >> 1) * 256 + f);
            ax += sa * bf2f(va.x);
            ay += sa * bf2f(va.y);
            az += sa * bf2f(va.z);
            aw += sa * bf2f(va.w);
        }
        ushort4 r;
        r.x = f2bf(ax); r.y = f2bf(ay); r.z = f2bf(az); r.w = f2bf(aw);
        *(ushort4*)(sbuf + (size_t)n * 256 + f) = r;
    } else {
        int t = (blockIdx.x - ZN_BLOCKS) * 4 + (threadIdx.x >> 6);
        int e0 = te[3 * t + 0], e1 = te[3 * t + 1], e2 = te[3 * t + 2];
        float s0 = (float)ts[3 * t + 0];
        float s1 = (float)ts[3 * t + 1];
        float s2 = (float)ts[3 * t + 2];
        ushort4 a4 = *(const ushort4*)(xb + (size_t)e0 * 256 + f);
        ushort4 b4 = *(const ushort4*)(xb + (size_t)e1 * 256 + f);
        ushort4 d4 = *(const ushort4*)(xb + (size_t)e2 * 256 + f);
        ushort4 r;
        r.x = f2bf(s0 * bf2f(a4.x) + s1 * bf2f(b4.x) + s2 * bf2f(d4.x));
        r.y = f2bf(s0 * bf2f(a4.y) + s1 * bf2f(b4.y) + s2 * bf2f(d4.y));
        r.z = f2bf(s0 * bf2f(a4.z) + s1 * bf2f(b4.z) + s2 * bf2f(d4.z));
        r.w = f2bf(s0 * bf2f(a4.w) + s1 * bf2f(b4.w) + s2 * bf2f(d4.w));
        *(ushort4*)(qbuf + (size_t)t * 256 + f) = r;
    }
}

// ---------------------------------------------------------------------------
// x_next[e] = relu( y1[e] + sum s*w[t] + z[v]-z[u] )
// ---------------------------------------------------------------------------
__global__ __launch_bounds__(256) void relu_fused(
    const unsigned short* __restrict__ y1,
    const unsigned short* __restrict__ w,
    const unsigned short* __restrict__ z,
    const int* __restrict__ en,
    const int* __restrict__ eoff,
    const int* __restrict__ eadj,
    unsigned short* __restrict__ xb)
{
    int e = blockIdx.x * 4 + (threadIdx.x >> 6);
    int lane = threadIdx.x & 63;
    int f = lane * 4;
    int u = en[2 * e], v = en[2 * e + 1];
    int beg = eoff[e], end = eoff[e + 1];
    ushort4 a4 = *(const ushort4*)(y1 + (size_t)e * 256 + f);
    ushort4 zv = *(const ushort4*)(z + (size_t)v * 256 + f);
    ushort4 zu = *(const ushort4*)(z + (size_t)u * 256 + f);
    float sx = bf2f(a4.x) + bf2f(zv.x) - bf2f(zu.x);
    float sy = bf2f(a4.y) + bf2f(zv.y) - bf2f(zu.y);
    float sz = bf2f(a4.z) + bf2f(zv.z) - bf2f(zu.z);
    float sw = bf2f(a4.w) + bf2f(zv.w) - bf2f(zu.w);
    int i = beg;
    for (; i + 1 < end; i += 2) {
        int ta = eadj[i], tb = eadj[i + 1];
        float sa = (ta & 1) ? -1.f : 1.f;
        float sgb = (tb & 1) ? -1.f : 1.f;
        ushort4 wa = *(const ushort4*)(w + (size_t)(ta >> 1) * 256 + f);
        ushort4 wbv = *(const ushort4*)(w + (size_t)(tb >> 1) * 256 + f);
        sx += sa * bf2f(wa.x) + sgb * bf2f(wbv.x);
        sy += sa * bf2f(wa.y) + sgb * bf2f(wbv.y);
        sz += sa * bf2f(wa.z) + sgb * bf2f(wbv.z);
        sw += sa * bf2f(wa.w) + sgb * bf2f(wbv.w);
    }
    if (i < end) {
        int ta = eadj[i];
        float sa = (ta & 1) ? -1.f : 1.f;
        ushort4 wa = *(const ushort4*)(w + (size_t)(ta >> 1) * 256 + f);
        sx += sa * bf2f(wa.x);
        sy += sa * bf2f(wa.y);
        sz += sa * bf2f(wa.z);
        sw += sa * bf2f(wa.w);
    }
    ushort4 r;
    r.x = f2bf(fmaxf(sx, 0.f));
    r.y = f2bf(fmaxf(sy, 0.f));
    r.z = f2bf(fmaxf(sz, 0.f));
    r.w = f2bf(fmaxf(sw, 0.f));
    *(ushort4*)(xb + (size_t)e * 256 + f) = r;
}

// ---------------------------------------------------------------------------
// p[e] = x[e] . W0_L ; out[n] = sum (+/-) p[e]
// ---------------------------------------------------------------------------
__global__ __launch_bounds__(256) void dotp(
    const unsigned short* __restrict__ xb,
    const float* __restrict__ wl,
    float* __restrict__ p)
{
    int e = blockIdx.x * 4 + (threadIdx.x >> 6);
    int lane = threadIdx.x & 63;
    ushort4 xv = *(const ushort4*)(xb + (size_t)e * 256 + lane * 4);
    float4 wv = *(const float4*)(wl + lane * 4);
    float s = bf2f(xv.x) * wv.x + bf2f(xv.y) * wv.y +
              bf2f(xv.z) * wv.z + bf2f(xv.w) * wv.w;
#pragma unroll
    for (int off = 32; off > 0; off >>= 1)
        s += __shfl_down(s, off, 64);
    if (lane == 0) p[e] = s;
}

__global__ __launch_bounds__(256) void out_nodes(
    const float* __restrict__ p,
    const int* __restrict__ noff,
    const int* __restrict__ nadj,
    float* __restrict__ out)
{
    int n = blockIdx.x * 256 + threadIdx.x;
    if (n >= NN_NODES) return;
    int beg = noff[n], end = noff[n + 1];
    float s = 0.f;
    for (int i = beg; i < end; i++) {
        int ent = nadj[i];
        float sg = (ent & 1) ? 1.f : -1.f;
        s += sg * p[ent >> 1];
    }
    out[n] = s;
}

// ---------------------------------------------------------------------------
// Conversions
// ---------------------------------------------------------------------------
__global__ __launch_bounds__(256) void cvt_x(
    const float* __restrict__ x, unsigned short* __restrict__ xb)
{
    int idx = blockIdx.x * 256 + threadIdx.x;
    float4 v = *(const float4*)(x + (size_t)idx * 4);
    ushort4 r;
    r.x = f2bf(v.x); r.y = f2bf(v.y); r.z = f2bf(v.z); r.w = f2bf(v.w);
    *(ushort4*)(xb + (size_t)idx * 4) = r;
}

// wt[l][seg][n][k], seg order = (W1, W0, W2)
__global__ __launch_bounds__(256) void cvt_w(
    const float* __restrict__ W0, const float* __restrict__ W1,
    const float* __restrict__ W2, unsigned short* __restrict__ wt)
{
    int idx = blockIdx.x * 256 + threadIdx.x;   // 4*3*65536 total
    int l = idx / (3 * 65536);
    int rem = idx - l * (3 * 65536);
    int seg = rem >> 16;
    int n = (rem >> 8) & 255;
    int k = rem & 255;
    const float* src = (seg == 0) ? W1 : (seg == 1) ? W0 : W2;
    wt[idx] = f2bf(src[(size_t)l * 65536 + k * 256 + n]);
}

extern "C" void kernel_launch(void* const* d_in, const int* in_sizes, int n_in,
                              void* d_out, int out_size, void* d_ws, size_t ws_size,
                              hipStream_t stream)
{
    const float* x0  = (const float*)d_in[0];
    const float* W0s = (const float*)d_in[1];
    const float* W1s = (const float*)d_in[2];
    const float* W2s = (const float*)d_in[3];
    const float* WL  = (const float*)d_in[4];
    const int*   en  = (const int*)d_in[5];
    const int*   te  = (const int*)d_in[6];
    const int*   ts  = (const int*)d_in[7];
    float* out = (float*)d_out;

    const size_t MF = (size_t)M_EDGES * F;
    unsigned short* xb = (unsigned short*)d_ws;          // MF
    unsigned short* y1 = xb + MF;                        // MF
    unsigned short* sbuf = y1 + MF;                      // NN*256
    unsigned short* qbuf = sbuf + (size_t)NN_NODES * 256;// N_TRIS*256
    unsigned short* wt = qbuf + (size_t)N_TRIS * 256;    // 4*3*65536
    unsigned short* wb = wt + (size_t)4 * 3 * 65536;     // N_TRIS*256
    unsigned short* zb = wb + (size_t)N_TRIS * 256;      // NN*256
    float* p = (float*)(zb + (size_t)NN_NODES * 256);    // M f32
    int* noff = (int*)(p + M_EDGES);                     // NN+1
    int* ncur = noff + (NN_NODES + 1);                   // NN
    int* nadj = ncur + NN_NODES;                         // 2*M
    int* eoff = nadj + 2 * M_EDGES;                      // M+1
    int* ecur = eoff + (M_EDGES + 1);                    // M
    int* eadj = ecur + M_EDGES;                          // 3*N_TRIS
    int* part = eadj + 3 * N_TRIS;                       // 1024

    cvt_w<<<(4 * 3 * 65536) / 256, 256, 0, stream>>>(W0s, W1s, W2s, wt);
    cvt_x<<<(int)(MF / 4 / 256), 256, 0, stream>>>(x0, xb);

    const int nbN = (NN_NODES + 255) / 256;
    const int nbE = (M_EDGES + 255) / 256;
    hipMemsetAsync(ncur, 0, NN_NODES * sizeof(int), stream);
    hipMemsetAsync(ecur, 0, M_EDGES * sizeof(int), stream);
    count_nodes<<<nbE, 256, 0, stream>>>(en, ncur);
    count_tris<<<(N_TRIS + 255) / 256, 256, 0, stream>>>(te, ecur);
    scan_block<<<nbN, 256, 0, stream>>>(ncur, noff, part, NN_NODES);
    scan_partial<<<1, 1024, 0, stream>>>(part, nbN);
    scan_add<<<nbN, 256, 0, stream>>>(noff, ncur, part, NN_NODES, 2 * M_EDGES);
    fill_nodes<<<nbE, 256, 0, stream>>>(en, ncur, nadj);
    scan_block<<<nbE, 256, 0, stream>>>(ecur, eoff, part, M_EDGES);
    scan_partial<<<1, 1024, 0, stream>>>(part, nbE);
    scan_add<<<nbE, 256, 0, stream>>>(eoff, ecur, part, M_EDGES, 3 * N_TRIS);
    fill_tris<<<(N_TRIS + 255) / 256, 256, 0, stream>>>(te, ts, ecur, eadj);

    for (int l = 0; l < NLAYERS; l++) {
        const unsigned short* wl_ = wt + (size_t)l * 3 * 65536;
        agg_fused<<<ZN_BLOCKS + WT_BLOCKS, 256, 0, stream>>>(
            xb, noff, nadj, sbuf, te, ts, qbuf);
        gemm_mfma<<<NTILES, 256, 0, stream>>>(
            xb, sbuf, qbuf, wl_, y1, zb, wb);
        relu_fused<<<M_EDGES / 4, 256, 0, stream>>>(y1, wb, zb, en, eoff, eadj, xb);
    }

    dotp<<<M_EDGES / 4, 256, 0, stream>>>(xb, WL, p);
    out_nodes<<<(NN_NODES + 255) / 256, 256, 0, stream>>>(p, noff, nadj, out);
}

// Round 10
// 1360.405 us; speedup vs baseline: 1.5661x; 1.0153x over previous
//
#include <hip/hip_runtime.h>

#define M_EDGES 150000
#define NN_NODES 50000
#define N_TRIS  100000
#define F 256
#define NLAYERS 4

#define T0 1172                  // ceil(150000/128)
#define T1 391                   // ceil(50000/128)
#define T2 782                   // ceil(100000/128)
#define T0_PAD 1176
#define G0_BLOCKS (T0_PAD * 2)   // 2352
#define T12 (T1 + T2)            // 1173
#define T12_PAD 1176
#define G12_BLOCKS (T12_PAD * 2) // 2352

#define ZN_BLOCKS (NN_NODES / 4) // 12500
#define WT_BLOCKS (N_TRIS / 4)   // 25000

typedef __attribute__((ext_vector_type(8))) __bf16 bf16x8;
typedef __attribute__((ext_vector_type(4))) float f32x4;

__device__ inline unsigned short f2bf(float f) {
    unsigned int u = __float_as_uint(f);
    u += 0x7fff + ((u >> 16) & 1);
    return (unsigned short)(u >> 16);
}
__device__ inline float bf2f(unsigned short h) {
    return __uint_as_float(((unsigned int)h) << 16);
}

__device__ inline void async16(const void* g, void* l) {
    __builtin_amdgcn_global_load_lds(
        (const __attribute__((address_space(1))) void*)g,
        (__attribute__((address_space(3))) void*)l, 16, 0, 0);
}

// ---------------------------------------------------------------------------
// r7-frozen GEMM K-loop: 128x128 C-tile, BK=32, XOR-swizzled LDS (r4:
// conflicts 7.2M->0), swapped-operand MFMA (lane holds row lm, cols lh*4+reg).
// r9 lesson: do NOT fatten blocks (VGPR/LDS -> occupancy cliff); this 68-VGPR
// 16KB-LDS shape at ~4700 blocks is the TLP sweet spot.
// ---------------------------------------------------------------------------
__device__ inline void gemm_kloop(
    const unsigned short* __restrict__ Asrc, int nrows,
    const unsigned short* __restrict__ wseg,   // [n][k] 256x256
    int bm0, int bn,
    unsigned short* As, unsigned short* Bs,
    f32x4 cacc[4][4])
{
    const int tid  = threadIdx.x;
    const int wid  = tid >> 6;
    const int lane = tid & 63;
    const int lm   = lane & 15;
    const int lh   = lane >> 4;
    const int wm   = wid >> 1;
    const int wn   = wid & 1;
    const int wbase = tid & ~63;

    for (int k0 = 0; k0 < 256; k0 += 32) {
#pragma unroll
        for (int s = 0; s < 2; s++) {
            int i   = s * 256 + tid;
            int row = i >> 2;
            int g   = (i & 3) ^ ((row >> 1) & 3);
            int gr  = bm0 + row;
            if (gr > nrows - 1) gr = nrows - 1;
            async16(Asrc + (size_t)gr * 256 + k0 + g * 8,
                    As + (size_t)(s * 256 + wbase) * 8);
            int nrow = bn * 128 + row;
            async16(wseg + (size_t)nrow * 256 + k0 + g * 8,
                    Bs + (size_t)(s * 256 + wbase) * 8);
        }
        asm volatile("s_waitcnt vmcnt(0)" ::: "memory");
        __syncthreads();

        bf16x8 a[4], bfr[4];
#pragma unroll
        for (int i = 0; i < 4; i++) {
            int rr = wm * 64 + i * 16 + lm;
            a[i] = *(const bf16x8*)(As + rr * 32 + ((lh ^ ((rr >> 1) & 3)) * 8));
        }
#pragma unroll
        for (int j = 0; j < 4; j++) {
            int rr = wn * 64 + j * 16 + lm;
            bfr[j] = *(const bf16x8*)(Bs + rr * 32 + ((lh ^ ((rr >> 1) & 3)) * 8));
        }
#pragma unroll
        for (int i = 0; i < 4; i++)
#pragma unroll
            for (int j = 0; j < 4; j++)
                cacc[i][j] = __builtin_amdgcn_mfma_f32_16x16x32_bf16(bfr[j], a[i], cacc[i][j], 0, 0, 0);
        __syncthreads();
    }
}

// ---------------------------------------------------------------------------
// gemm12: seg1: z = s @ W0 (50k rows), seg2: w = q @ W2 (100k rows).
// Plain bf16-store epilogue.
// ---------------------------------------------------------------------------
__global__ __launch_bounds__(256) void gemm12(
    const unsigned short* __restrict__ sb,
    const unsigned short* __restrict__ qb,
    const unsigned short* __restrict__ wt,
    unsigned short* __restrict__ zb,
    unsigned short* __restrict__ wb)
{
    __shared__ unsigned short As[128 * 32];
    __shared__ unsigned short Bs[128 * 32];

    const int b    = blockIdx.x;
    const int xcd  = b & 7;
    const int c    = b >> 3;
    const int tile = (c >> 1) * 8 + xcd;
    const int bn   = c & 1;
    if (tile >= T12) return;

    const unsigned short* Asrc;
    const unsigned short* wseg;
    unsigned short* dst;
    int nrows, tloc;
    if (tile < T1) { Asrc = sb; wseg = wt + 65536;  dst = zb; nrows = NN_NODES; tloc = tile; }
    else           { Asrc = qb; wseg = wt + 131072; dst = wb; nrows = N_TRIS;   tloc = tile - T1; }

    f32x4 cacc[4][4];
#pragma unroll
    for (int i = 0; i < 4; i++)
#pragma unroll
        for (int j = 0; j < 4; j++) cacc[i][j] = (f32x4){0.f, 0.f, 0.f, 0.f};

    const int bm0 = tloc * 128;
    gemm_kloop(Asrc, nrows, wseg, bm0, bn, As, Bs, cacc);

    const int tid  = threadIdx.x;
    const int lane = tid & 63;
    const int lm   = lane & 15;
    const int lh   = lane >> 4;
    const int wm   = (tid >> 6) >> 1;
    const int wn   = (tid >> 6) & 1;
#pragma unroll
    for (int i = 0; i < 4; i++) {
        int grow = bm0 + wm * 64 + i * 16 + lm;
        if (grow < nrows) {
#pragma unroll
            for (int j = 0; j < 4; j++) {
                int col = bn * 128 + wn * 64 + j * 16 + lh * 4;
                ushort4 r;
                r.x = f2bf(cacc[i][j][0]);
                r.y = f2bf(cacc[i][j][1]);
                r.z = f2bf(cacc[i][j][2]);
                r.w = f2bf(cacc[i][j][3]);
                *(ushort4*)(dst + (size_t)grow * 256 + col) = r;
            }
        }
    }
}

// ---------------------------------------------------------------------------
// gemm0_relu: seg0 GEMM (x @ W1, 150k rows) with FUSED ReLU epilogue:
//   x_next[e,col] = relu( y1[e,col] + z[v,col]-z[u,col] + sum_t +/- w[t,col] )
// y1 never touches memory (and stays f32 into the sum). Depends on gemm12's
// z/w, hence a separate launch. Writes to the alternate x buffer.
// ---------------------------------------------------------------------------
__global__ __launch_bounds__(256) void gemm0_relu(
    const unsigned short* __restrict__ xin,
    const unsigned short* __restrict__ wt,     // seg0 = W1
    const unsigned short* __restrict__ zb,
    const unsigned short* __restrict__ wb,
    const int* __restrict__ en,
    const int* __restrict__ eoff,
    const int* __restrict__ eadj,
    unsigned short* __restrict__ xout)
{
    __shared__ unsigned short As[128 * 32];
    __shared__ unsigned short Bs[128 * 32];

    const int b    = blockIdx.x;
    const int xcd  = b & 7;
    const int c    = b >> 3;
    const int tile = (c >> 1) * 8 + xcd;
    const int bn   = c & 1;
    if (tile >= T0) return;

    f32x4 cacc[4][4];
#pragma unroll
    for (int i = 0; i < 4; i++)
#pragma unroll
        for (int j = 0; j < 4; j++) cacc[i][j] = (f32x4){0.f, 0.f, 0.f, 0.f};

    const int bm0 = tile * 128;
    gemm_kloop(xin, M_EDGES, wt, bm0, bn, As, Bs, cacc);

    const int tid  = threadIdx.x;
    const int lane = tid & 63;
    const int lm   = lane & 15;
    const int lh   = lane >> 4;
    const int wm   = (tid >> 6) >> 1;
    const int wn   = (tid >> 6) & 1;
    const int colb = bn * 128 + wn * 64 + lh * 4;

#pragma unroll
    for (int i = 0; i < 4; i++) {
        int e = bm0 + wm * 64 + i * 16 + lm;
        if (e < M_EDGES) {
            int u = en[2 * e], v = en[2 * e + 1];
            int beg = eoff[e], end = eoff[e + 1];
            float s0[4], s1[4], s2[4], s3[4];
#pragma unroll
            for (int j = 0; j < 4; j++) {
                int col = colb + j * 16;
                ushort4 zvv = *(const ushort4*)(zb + (size_t)v * 256 + col);
                ushort4 zuu = *(const ushort4*)(zb + (size_t)u * 256 + col);
                s0[j] = cacc[i][j][0] + bf2f(zvv.x) - bf2f(zuu.x);
                s1[j] = cacc[i][j][1] + bf2f(zvv.y) - bf2f(zuu.y);
                s2[j] = cacc[i][j][2] + bf2f(zvv.z) - bf2f(zuu.z);
                s3[j] = cacc[i][j][3] + bf2f(zvv.w) - bf2f(zuu.w);
            }
            for (int it = beg; it < end; it++) {
                int ent = eadj[it];
                float sg = (ent & 1) ? -1.f : 1.f;
                const unsigned short* wr = wb + (size_t)(ent >> 1) * 256;
#pragma unroll
                for (int j = 0; j < 4; j++) {
                    int col = colb + j * 16;
                    ushort4 wv = *(const ushort4*)(wr + col);
                    s0[j] += sg * bf2f(wv.x);
                    s1[j] += sg * bf2f(wv.y);
                    s2[j] += sg * bf2f(wv.z);
                    s3[j] += sg * bf2f(wv.w);
                }
            }
#pragma unroll
            for (int j = 0; j < 4; j++) {
                int col = colb + j * 16;
                ushort4 r;
                r.x = f2bf(fmaxf(s0[j], 0.f));
                r.y = f2bf(fmaxf(s1[j], 0.f));
                r.z = f2bf(fmaxf(s2[j], 0.f));
                r.w = f2bf(fmaxf(s3[j], 0.f));
                *(ushort4*)(xout + (size_t)e * 256 + col) = r;
            }
        }
    }
}

// ---------------------------------------------------------------------------
// CSR build
// ---------------------------------------------------------------------------
__global__ __launch_bounds__(256) void count_nodes(
    const int* __restrict__ en, int* __restrict__ cnt)
{
    int e = blockIdx.x * 256 + threadIdx.x;
    if (e < M_EDGES) {
        atomicAdd(&cnt[en[2 * e]], 1);
        atomicAdd(&cnt[en[2 * e + 1]], 1);
    }
}

__global__ __launch_bounds__(256) void count_tris(
    const int* __restrict__ te, int* __restrict__ cnt)
{
    int t = blockIdx.x * 256 + threadIdx.x;
    if (t < N_TRIS) {
#pragma unroll
        for (int k = 0; k < 3; k++) atomicAdd(&cnt[te[3 * t + k]], 1);
    }
}

__global__ __launch_bounds__(256) void scan_block(
    const int* __restrict__ cnt, int* __restrict__ off,
    int* __restrict__ partial, int n)
{
    __shared__ int s[256];
    int t = threadIdx.x;
    int gid = blockIdx.x * 256 + t;
    int v = (gid < n) ? cnt[gid] : 0;
    s[t] = v;
    __syncthreads();
    for (int o = 1; o < 256; o <<= 1) {
        int x = (t >= o) ? s[t - o] : 0;
        __syncthreads();
        s[t] += x;
        __syncthreads();
    }
    if (gid < n) off[gid] = s[t] - v;
    if (t == 255) partial[blockIdx.x] = s[255];
}

__global__ __launch_bounds__(1024) void scan_partial(int* __restrict__ partial, int nb)
{
    __shared__ int s[1024];
    int t = threadIdx.x;
    int v = (t < nb) ? partial[t] : 0;
    s[t] = v;
    __syncthreads();
    for (int o = 1; o < 1024; o <<= 1) {
        int x = (t >= o) ? s[t - o] : 0;
        __syncthreads();
        s[t] += x;
        __syncthreads();
    }
    if (t < nb) partial[t] = s[t] - v;
}

__global__ __launch_bounds__(256) void scan_add(
    int* __restrict__ off, int* __restrict__ cursor,
    const int* __restrict__ partial, int n, int total)
{
    int gid = blockIdx.x * 256 + threadIdx.x;
    if (gid == 0) off[n] = total;
    if (gid < n) {
        int o = off[gid] + partial[blockIdx.x];
        off[gid] = o;
        cursor[gid] = o;
    }
}

__global__ __launch_bounds__(256) void fill_nodes(
    const int* __restrict__ en, int* __restrict__ cursor, int* __restrict__ adj)
{
    int e = blockIdx.x * 256 + threadIdx.x;
    if (e < M_EDGES) {
        int u = en[2 * e], v = en[2 * e + 1];
        adj[atomicAdd(&cursor[u], 1)] = (e << 1);        // u endpoint: minus
        adj[atomicAdd(&cursor[v], 1)] = (e << 1) | 1;    // v endpoint: plus
    }
}

__global__ __launch_bounds__(256) void fill_tris(
    const int* __restrict__ te, const int* __restrict__ ts,
    int* __restrict__ cursor, int* __restrict__ adj)
{
    int t = blockIdx.x * 256 + threadIdx.x;
    if (t < N_TRIS) {
#pragma unroll
        for (int k = 0; k < 3; k++) {
            int e = te[3 * t + k];
            int neg = (ts[3 * t + k] < 0) ? 1 : 0;
            adj[atomicAdd(&cursor[e], 1)] = (t << 1) | neg;
        }
    }
}

// ---------------------------------------------------------------------------
// Aggregation pass (pre-GEMM):
//   blocks [0, ZN_BLOCKS) : s[n] = sum (+/-) x[e]
//   blocks [ZN, +WT)      : q[t] = sum s_k * x[e_k]
// ---------------------------------------------------------------------------
__global__ __launch_bounds__(256) void agg_fused(
    const unsigned short* __restrict__ xb,
    const int* __restrict__ noff,
    const int* __restrict__ nadj,
    unsigned short* __restrict__ sbuf,
    const int* __restrict__ te,
    const int* __restrict__ ts,
    unsigned short* __restrict__ qbuf)
{
    int lane = threadIdx.x & 63;
    int f = lane * 4;
    if (blockIdx.x < ZN_BLOCKS) {
        int n = blockIdx.x * 4 + (threadIdx.x >> 6);
        int beg = noff[n], end = noff[n + 1];
        float ax = 0.f, ay = 0.f, az = 0.f, aw = 0.f;
        int i = beg;
        for (; i + 1 < end; i += 2) {
            int ea = nadj[i], eb = nadj[i + 1];
            float sa = (ea & 1) ? 1.f : -1.f;
            float sgb = (eb & 1) ? 1.f : -1.f;
            ushort4 va = *(const ushort4*)(xb + (size_t)(ea >> 1) * 256 + f);
            ushort4 vb = *(const ushort4*)(xb + (size_t)(eb >> 1) * 256 + f);
            ax += sa * bf2f(va.x) + sgb * bf2f(vb.x);
            ay += sa * bf2f(va.y) + sgb * bf2f(vb.y);
            az += sa * bf2f(va.z) + sgb * bf2f(vb.z);
            aw += sa * bf2f(va.w) + sgb * bf2f(vb.w);
        }
        if (i < end) {
            int ea = nadj[i];
            float sa = (ea & 1) ? 1.f : -1.f;
            ushort4 va = *(const ushort4*)(xb + (size_t)(ea >> 1) * 256 + f);
            ax += sa * bf2f(va.x);
            ay += sa * bf2f(va.y);
            az += sa * bf2f(va.z);
            aw += sa * bf2f(va.w);
        }
        ushort4 r;
        r.x = f2bf(ax); r.y = f2bf(ay); r.z = f2bf(az); r.w = f2bf(aw);
        *(ushort4*)(sbuf + (size_t)n * 256 + f) = r;
    } else {
        int t = (blockIdx.x - ZN_BLOCKS) * 4 + (threadIdx.x >> 6);
        int e0 = te[3 * t + 0], e1 = te[3 * t + 1], e2 = te[3 * t + 2];
        float s0 = (float)ts[3 * t + 0];
        float s1 = (float)ts[3 * t + 1];
        float s2 = (float)ts[3 * t + 2];
        ushort4 a4 = *(const ushort4*)(xb + (size_t)e0 * 256 + f);
        ushort4 b4 = *(const ushort4*)(xb + (size_t)e1 * 256 + f);
        ushort4 d4 = *(const ushort4*)(xb + (size_t)e2 * 256 + f);
        ushort4 r;
        r.x = f2bf(s0 * bf2f(a4.x) + s1 * bf2f(b4.x) + s2 * bf2f(d4.x));
        r.y = f2bf(s0 * bf2f(a4.y) + s1 * bf2f(b4.y) + s2 * bf2f(d4.y));
        r.z = f2bf(s0 * bf2f(a4.z) + s1 * bf2f(b4.z) + s2 * bf2f(d4.z));
        r.w = f2bf(s0 * bf2f(a4.w) + s1 * bf2f(b4.w) + s2 * bf2f(d4.w));
        *(ushort4*)(qbuf + (size_t)t * 256 + f) = r;
    }
}

// ---------------------------------------------------------------------------
// p[e] = x[e] . W0_L ; out[n] = sum (+/-) p[e]
// ---------------------------------------------------------------------------
__global__ __launch_bounds__(256) void dotp(
    const unsigned short* __restrict__ xb,
    const float* __restrict__ wl,
    float* __restrict__ p)
{
    int e = blockIdx.x * 4 + (threadIdx.x >> 6);
    int lane = threadIdx.x & 63;
    ushort4 xv = *(const ushort4*)(xb + (size_t)e * 256 + lane * 4);
    float4 wv = *(const float4*)(wl + lane * 4);
    float s = bf2f(xv.x) * wv.x + bf2f(xv.y) * wv.y +
              bf2f(xv.z) * wv.z + bf2f(xv.w) * wv.w;
#pragma unroll
    for (int off = 32; off > 0; off >>= 1)
        s += __shfl_down(s, off, 64);
    if (lane == 0) p[e] = s;
}

__global__ __launch_bounds__(256) void out_nodes(
    const float* __restrict__ p,
    const int* __restrict__ noff,
    const int* __restrict__ nadj,
    float* __restrict__ out)
{
    int n = blockIdx.x * 256 + threadIdx.x;
    if (n >= NN_NODES) return;
    int beg = noff[n], end = noff[n + 1];
    float s = 0.f;
    for (int i = beg; i < end; i++) {
        int ent = nadj[i];
        float sg = (ent & 1) ? 1.f : -1.f;
        s += sg * p[ent >> 1];
    }
    out[n] = s;
}

// ---------------------------------------------------------------------------
// Conversions
// ---------------------------------------------------------------------------
__global__ __launch_bounds__(256) void cvt_x(
    const float* __restrict__ x, unsigned short* __restrict__ xb)
{
    int idx = blockIdx.x * 256 + threadIdx.x;
    float4 v = *(const float4*)(x + (size_t)idx * 4);
    ushort4 r;
    r.x = f2bf(v.x); r.y = f2bf(v.y); r.z = f2bf(v.z); r.w = f2bf(v.w);
    *(ushort4*)(xb + (size_t)idx * 4) = r;
}

// wt[l][seg][n][k], seg order = (W1, W0, W2)
__global__ __launch_bounds__(256) void cvt_w(
    const float* __restrict__ W0, const float* __restrict__ W1,
    const float* __restrict__ W2, unsigned short* __restrict__ wt)
{
    int idx = blockIdx.x * 256 + threadIdx.x;   // 4*3*65536 total
    int l = idx / (3 * 65536);
    int rem = idx - l * (3 * 65536);
    int seg = rem >> 16;
    int n = (rem >> 8) & 255;
    int k = rem & 255;
    const float* src = (seg == 0) ? W1 : (seg == 1) ? W0 : W2;
    wt[idx] = f2bf(src[(size_t)l * 65536 + k * 256 + n]);
}

extern "C" void kernel_launch(void* const* d_in, const int* in_sizes, int n_in,
                              void* d_out, int out_size, void* d_ws, size_t ws_size,
                              hipStream_t stream)
{
    const float* x0  = (const float*)d_in[0];
    const float* W0s = (const float*)d_in[1];
    const float* W1s = (const float*)d_in[2];
    const float* W2s = (const float*)d_in[3];
    const float* WL  = (const float*)d_in[4];
    const int*   en  = (const int*)d_in[5];
    const int*   te  = (const int*)d_in[6];
    const int*   ts  = (const int*)d_in[7];
    float* out = (float*)d_out;

    const size_t MF = (size_t)M_EDGES * F;
    unsigned short* xb  = (unsigned short*)d_ws;          // MF (x ping)
    unsigned short* xb2 = xb + MF;                        // MF (x pong)
    unsigned short* sbuf = xb2 + MF;                      // NN*256
    unsigned short* qbuf = sbuf + (size_t)NN_NODES * 256; // N_TRIS*256
    unsigned short* wt = qbuf + (size_t)N_TRIS * 256;     // 4*3*65536
    unsigned short* wb = wt + (size_t)4 * 3 * 65536;      // N_TRIS*256
    unsigned short* zb = wb + (size_t)N_TRIS * 256;       // NN*256
    float* p = (float*)(zb + (size_t)NN_NODES * 256);     // M f32
    int* noff = (int*)(p + M_EDGES);                      // NN+1
    int* ncur = noff + (NN_NODES + 1);                    // NN
    int* nadj = ncur + NN_NODES;                          // 2*M
    int* eoff = nadj + 2 * M_EDGES;                       // M+1
    int* ecur = eoff + (M_EDGES + 1);                     // M
    int* eadj = ecur + M_EDGES;                           // 3*N_TRIS
    int* part = eadj + 3 * N_TRIS;                        // 1024

    cvt_w<<<(4 * 3 * 65536) / 256, 256, 0, stream>>>(W0s, W1s, W2s, wt);
    cvt_x<<<(int)(MF / 4 / 256), 256, 0, stream>>>(x0, xb);

    const int nbN = (NN_NODES + 255) / 256;
    const int nbE = (M_EDGES + 255) / 256;
    hipMemsetAsync(ncur, 0, NN_NODES * sizeof(int), stream);
    hipMemsetAsync(ecur, 0, M_EDGES * sizeof(int), stream);
    count_nodes<<<nbE, 256, 0, stream>>>(en, ncur);
    count_tris<<<(N_TRIS + 255) / 256, 256, 0, stream>>>(te, ecur);
    scan_block<<<nbN, 256, 0, stream>>>(ncur, noff, part, NN_NODES);
    scan_partial<<<1, 1024, 0, stream>>>(part, nbN);
    scan_add<<<nbN, 256, 0, stream>>>(noff, ncur, part, NN_NODES, 2 * M_EDGES);
    fill_nodes<<<nbE, 256, 0, stream>>>(en, ncur, nadj);
    scan_block<<<nbE, 256, 0, stream>>>(ecur, eoff, part, M_EDGES);
    scan_partial<<<1, 1024, 0, stream>>>(part, nbE);
    scan_add<<<nbE, 256, 0, stream>>>(eoff, ecur, part, M_EDGES, 3 * N_TRIS);
    fill_tris<<<(N_TRIS + 255) / 256, 256, 0, stream>>>(te, ts, ecur, eadj);

    for (int l = 0; l < NLAYERS; l++) {
        const unsigned short* wl_ = wt + (size_t)l * 3 * 65536;
        const unsigned short* xin = (l & 1) ? xb2 : xb;
        unsigned short* xout      = (l & 1) ? xb : xb2;
        agg_fused<<<ZN_BLOCKS + WT_BLOCKS, 256, 0, stream>>>(
            xin, noff, nadj, sbuf, te, ts, qbuf);
        gemm12<<<G12_BLOCKS, 256, 0, stream>>>(sbuf, qbuf, wl_, zb, wb);
        gemm0_relu<<<G0_BLOCKS, 256, 0, stream>>>(
            xin, wl_, zb, wb, en, eoff, eadj, xout);
    }

    // after 4 layers final x is in xb (l=3 wrote xout=xb)
    dotp<<<M_EDGES / 4, 256, 0, stream>>>(xb, WL, p);
    out_nodes<<<(NN_NODES + 255) / 256, 256, 0, stream>>>(p, noff, nadj, out);
}